// Round 4
// baseline (174.567 us; speedup 1.0000x reference)
//
#include <hip/hip_runtime.h>

#define D 128
#define TILE_M 64
#define BS_STRIDE 129
#define AS_STRIDE 68
#define WS_STRIDE 136   // shorts; 272 B rows -> 16 B aligned, banks spread
#define DS_STRIDE 136
#define GEMM_BLOCKS 768    // == 256 CU x 3 blocks/CU (52 KB LDS) -> fully co-resident;
                           // %8==0 preserves blockIdx&7 parity for XCD range ownership
#define CAP 64             // padded CSR row capacity (max degree ~35; 64 = 12 sigma)

typedef __attribute__((ext_vector_type(8))) short short8;
typedef __attribute__((ext_vector_type(4))) float floatx4;
typedef __attribute__((ext_vector_type(4))) unsigned short ushortx4;

__device__ __forceinline__ unsigned short f2bf(float f) {
    unsigned u = __float_as_uint(f);
    u += 0x7fffu + ((u >> 16) & 1u);   // round-to-nearest-even
    return (unsigned short)(u >> 16);
}

// ---------------- fused bucket -> GEMM (r2 structure, known 54us) ----------------
// r15: bucket wall diagnosed (r14): 800K returning atomics + scattered 4B stores are
// ~46us standalone at ANY occupancy; WRITE_SIZE ~47MB is the atomic/RMW traffic itself,
// invariant to ep layout. Fusion with the GEMM overlaps ~9us of it -> keep r2's fused
// form exactly. THIS round's change is on the gather side: tf is now stored
// COLUMN-BLOCKED: tf_cb[x][node][16 cols], x = 0..7, so each 16-col slice is 1.6MB
// and can sit resident in one XCD's 4MB L2 during the gather.
// Edge record = 4B: [31:16] = bf16(w), [15:0] = src (needs N <= 65536).
__global__ __launch_bounds__(256) void gemm_bucket(
    const float* __restrict__ feat, const float* __restrict__ Wm,
    unsigned short* __restrict__ tf,
    const int* __restrict__ src, const int* __restrict__ dst,
    const float* __restrict__ w, int* __restrict__ cnt,
    unsigned* __restrict__ ep, int N, int E)
{
    __shared__ unsigned short Ws[128 * WS_STRIDE];  // 34816 B
    __shared__ unsigned short Ds[64 * DS_STRIDE];   // 17408 B

    // ---- phase 1: bucket (all blocks). int4/float4 edge scan, XCD-range ownership ----
    {
        const int xcd = blockIdx.x & 7;
        const int blk = blockIdx.x >> 3;          // 0..95 within the XCD group
        const int nblk = GEMM_BLOCKS >> 3;        // 96
        const int lo = (int)((long long)xcd * N / 8);
        const int hi = (int)((long long)(xcd + 1) * N / 8);
        const int E4 = E & ~3;
        for (int e4 = (blk * 256 + threadIdx.x) * 4; e4 < E4; e4 += nblk * 256 * 4) {
            const int4   d4 = *reinterpret_cast<const int4*>(dst + e4);
            const int4   s4 = *reinterpret_cast<const int4*>(src + e4);
            const float4 w4 = *reinterpret_cast<const float4*>(w + e4);
#pragma unroll
            for (int j = 0; j < 4; ++j) {
                int   d  = (j == 0) ? d4.x : (j == 1) ? d4.y : (j == 2) ? d4.z : d4.w;
                if (d >= lo && d < hi) {
                    int   sj = (j == 0) ? s4.x : (j == 1) ? s4.y : (j == 2) ? s4.z : s4.w;
                    float wj = (j == 0) ? w4.x : (j == 1) ? w4.y : (j == 2) ? w4.z : w4.w;
                    unsigned rec = ((unsigned)f2bf(wj) << 16) | (unsigned)sj;
                    int pos = atomicAdd(&cnt[d], 1);
                    if (pos < CAP)
                        ep[(size_t)pos * (size_t)N + (size_t)d] = rec;   // plane-major
                }
            }
        }
        // tail (E not multiple of 4): one thread per XCD group
        if (threadIdx.x == 0 && blk == 0) {
            for (int e = E4; e < E; ++e) {
                int d = dst[e];
                if (d >= lo && d < hi) {
                    unsigned rec = ((unsigned)f2bf(w[e]) << 16) | (unsigned)src[e];
                    int pos = atomicAdd(&cnt[d], 1);
                    if (pos < CAP)
                        ep[(size_t)pos * (size_t)N + (size_t)d] = rec;
                }
            }
        }
    }

    // ---- phase 2: GEMM (all blocks) ----
    const int tid = threadIdx.x;
    for (int idx = tid; idx < 128 * 128 / 4; idx += 256) {
        int r = idx >> 5;
        int c = (idx & 31) * 4;
        const float4 v = reinterpret_cast<const float4*>(Wm)[idx];
        ushortx4 s;
        s[0] = f2bf(v.x); s[1] = f2bf(v.y); s[2] = f2bf(v.z); s[3] = f2bf(v.w);
        *reinterpret_cast<ushortx4*>(&Ws[r * WS_STRIDE + c]) = s;
    }
    __syncthreads();

    const int lane = tid & 63;
    const int wave = tid >> 6;
    const int kq = (lane >> 4) * 8;
    const int ntiles = (N + 63) >> 6;

    for (int t = blockIdx.x; t < ntiles; t += GEMM_BLOCKS) {
        const int node0 = t * 64;
        const int mr = node0 + wave * 16 + (lane & 15);
        const float* arow = feat + (size_t)(mr < N ? mr : (N - 1)) * D + kq;

        short8 a[4];
#pragma unroll
        for (int kt = 0; kt < 4; ++kt) {
            const float* p = arow + kt * 32;
            const float4 lo = *reinterpret_cast<const float4*>(p);
            const float4 hi = *reinterpret_cast<const float4*>(p + 4);
            short8 v;
            v[0] = (short)f2bf(lo.x); v[1] = (short)f2bf(lo.y);
            v[2] = (short)f2bf(lo.z); v[3] = (short)f2bf(lo.w);
            v[4] = (short)f2bf(hi.x); v[5] = (short)f2bf(hi.y);
            v[6] = (short)f2bf(hi.z); v[7] = (short)f2bf(hi.w);
            a[kt] = v;
        }

        floatx4 acc[8];
#pragma unroll
        for (int nt = 0; nt < 8; ++nt) {
            acc[nt][0] = 0.f; acc[nt][1] = 0.f; acc[nt][2] = 0.f; acc[nt][3] = 0.f;
        }
#pragma unroll
        for (int nt = 0; nt < 8; ++nt) {
            const unsigned short* brow = &Ws[(nt * 16 + (lane & 15)) * WS_STRIDE + kq];
#pragma unroll
            for (int kt = 0; kt < 4; ++kt) {
                short8 b = *reinterpret_cast<const short8*>(brow + kt * 32);
                acc[nt] = __builtin_amdgcn_mfma_f32_16x16x32_bf16(a[kt], b, acc[nt], 0, 0, 0);
            }
        }

        __syncthreads();   // prev tile's Ds readers done
        const int mlocal = wave * 16 + (lane >> 4) * 4;
        const int col = lane & 15;
#pragma unroll
        for (int r = 0; r < 4; ++r) {
            unsigned short* drow = &Ds[(mlocal + r) * DS_STRIDE + col];
#pragma unroll
            for (int nt = 0; nt < 8; ++nt)
                drow[nt * 16] = f2bf(acc[nt][r]);
        }
        __syncthreads();

        // 64 rows x 16 chunks of 16B -> column-blocked tf: slice x = chunk>>1 (16 cols),
        // within slice: node*16 ushorts + (chunk&1)*8. Per wave per slice the stores are
        // 4 adjacent nodes x 32B = 128B contiguous.
        for (int idx = tid; idx < 64 * 16; idx += 256) {
            int row = idx >> 4;
            int chunk = idx & 15;
            int m = node0 + row;
            if (m < N) {
                uint4 v = *reinterpret_cast<const uint4*>(&Ds[row * DS_STRIDE + chunk * 8]);
                int x = chunk >> 1;
                int h8 = (chunk & 1) << 3;
                *reinterpret_cast<uint4*>(tf + (size_t)x * (size_t)N * 16 +
                                          (size_t)m * 16 + h8) = v;
            }
        }
    }
}

// ---------------- column-blocked gather: out[:, x*16:(x+1)*16] = relu(sum w*tf_cb[x][src] + b) ----------------
// blockIdx&7 = slice x (round-robin dispatch -> XCD affinity heuristic): each XCD's
// blocks read ONLY slice x = 1.6MB, resident in its 4MB L2 -> the 205MB of tf row
// reads become L2 hits instead of L3 traffic. Cost: ep/cnt records decoded 8x
// (L3-served, 25.6MB) and 8x VALU decode redundancy. 2 lanes per node (16B = 8 bf16
// each); a lane-pair writes one full 64B out line. 8 planes unrolled per lane.
__global__ __launch_bounds__(256) void csr_gather_cb(
    const unsigned short* __restrict__ tf, const unsigned* __restrict__ ep,
    const int* __restrict__ cnt, const float* __restrict__ bias,
    float* __restrict__ out, int N)
{
    const int x = blockIdx.x & 7;
    const int node = (blockIdx.x >> 3) * 128 + (threadIdx.x >> 1);
    if (node >= N) return;
    const int h8 = (threadIdx.x & 1) << 3;                 // 0 or 8 ushorts
    const unsigned short* slice = tf + (size_t)x * (size_t)N * 16 + h8;
    const unsigned* col = ep + node;                        // stride N per plane
    int end = cnt[node];
    end = end < CAP ? end : CAP;
    int p = 0;
    float a0 = 0.f, a1 = 0.f, a2 = 0.f, a3 = 0.f;
    float a4 = 0.f, a5 = 0.f, a6 = 0.f, a7 = 0.f;

#define ACC8(Q, W)                                       \
    a0 += __uint_as_float((Q).x << 16) * (W);            \
    a1 += __uint_as_float((Q).x & 0xffff0000u) * (W);    \
    a2 += __uint_as_float((Q).y << 16) * (W);            \
    a3 += __uint_as_float((Q).y & 0xffff0000u) * (W);    \
    a4 += __uint_as_float((Q).z << 16) * (W);            \
    a5 += __uint_as_float((Q).z & 0xffff0000u) * (W);    \
    a6 += __uint_as_float((Q).w << 16) * (W);            \
    a7 += __uint_as_float((Q).w & 0xffff0000u) * (W);

    for (; p + 7 < end; p += 8) {
        unsigned r[8];
#pragma unroll
        for (int j = 0; j < 8; ++j) r[j] = col[(size_t)(p + j) * N];
        uint4 q[8];
        float wv[8];
#pragma unroll
        for (int j = 0; j < 8; ++j) {
            q[j] = *reinterpret_cast<const uint4*>(slice + (size_t)(r[j] & 0xffffu) * 16);
            wv[j] = __uint_as_float(r[j] & 0xffff0000u);
        }
#pragma unroll
        for (int j = 0; j < 8; ++j) { ACC8(q[j], wv[j]) }
    }
    for (; p + 3 < end; p += 4) {
        unsigned r[4];
#pragma unroll
        for (int j = 0; j < 4; ++j) r[j] = col[(size_t)(p + j) * N];
        uint4 q[4];
        float wv[4];
#pragma unroll
        for (int j = 0; j < 4; ++j) {
            q[j] = *reinterpret_cast<const uint4*>(slice + (size_t)(r[j] & 0xffffu) * 16);
            wv[j] = __uint_as_float(r[j] & 0xffff0000u);
        }
#pragma unroll
        for (int j = 0; j < 4; ++j) { ACC8(q[j], wv[j]) }
    }
    for (; p < end; ++p) {
        unsigned r = col[(size_t)p * N];
        float wv = __uint_as_float(r & 0xffff0000u);
        uint4 q = *reinterpret_cast<const uint4*>(slice + (size_t)(r & 0xffffu) * 16);
        ACC8(q, wv)
    }
#undef ACC8

    const float* bp = bias + x * 16 + h8;
    const float4 bv0 = *reinterpret_cast<const float4*>(bp);
    const float4 bv1 = *reinterpret_cast<const float4*>(bp + 4);
    float4 r0, r1;
    r0.x = fmaxf(a0 + bv0.x, 0.f);
    r0.y = fmaxf(a1 + bv0.y, 0.f);
    r0.z = fmaxf(a2 + bv0.z, 0.f);
    r0.w = fmaxf(a3 + bv0.w, 0.f);
    r1.x = fmaxf(a4 + bv1.x, 0.f);
    r1.y = fmaxf(a5 + bv1.y, 0.f);
    r1.z = fmaxf(a6 + bv1.z, 0.f);
    r1.w = fmaxf(a7 + bv1.w, 0.f);
    float* o = out + (size_t)node * D + x * 16 + h8;
    *reinterpret_cast<float4*>(o) = r0;
    *reinterpret_cast<float4*>(o + 4) = r1;
}

// ---------------- tier-1 fallback: atomic scatter + fp32 GEMM ----------------
__global__ __launch_bounds__(256) void edge_scatter(
    const float* __restrict__ feat, const int* __restrict__ src,
    const int* __restrict__ dst, const float* __restrict__ w,
    float* __restrict__ agg, int E)
{
    long long idx = (long long)blockIdx.x * 256 + threadIdx.x;
    int e = (int)(idx >> 5);
    if (e >= E) return;
    int c = ((int)idx & 31) << 2;
    int s = src[e];
    int d = dst[e];
    float wv = w[e];
    const float4 f = *reinterpret_cast<const float4*>(feat + (size_t)s * D + c);
    float* a = agg + (size_t)d * D + c;
    atomicAdd(a + 0, f.x * wv);
    atomicAdd(a + 1, f.y * wv);
    atomicAdd(a + 2, f.z * wv);
    atomicAdd(a + 3, f.w * wv);
}

__global__ __launch_bounds__(256) void node_linear(
    const float* __restrict__ in, const float* __restrict__ Wm,
    const float* __restrict__ bias, float* __restrict__ out, int N)
{
    __shared__ float Bs[64 * BS_STRIDE];
    __shared__ float As[TILE_M * AS_STRIDE];
    const int tid = threadIdx.x;
    const int tx = tid & 15;
    const int ty = tid >> 4;
    const int node0 = blockIdx.x * TILE_M;
    float acc[4][8];
#pragma unroll
    for (int i = 0; i < 4; ++i)
#pragma unroll
        for (int jj = 0; jj < 8; ++jj) acc[i][jj] = 0.0f;
    for (int kh = 0; kh < 2; ++kh) {
        const int kbase = kh * 64;
        for (int i = tid; i < 128 * 64; i += 256) {
            int j = i >> 6, k = i & 63;
            Bs[k * BS_STRIDE + j] = Wm[j * 128 + kbase + k];
        }
        for (int i = tid; i < TILE_M * 64; i += 256) {
            int m = i >> 6, k = i & 63;
            int n = node0 + m;
            As[m * AS_STRIDE + k] = (n < N) ? in[(size_t)n * D + kbase + k] : 0.0f;
        }
        __syncthreads();
        for (int k0 = 0; k0 < 64; k0 += 4) {
            float a[4][4];
#pragma unroll
            for (int i = 0; i < 4; ++i) {
                const float4 v = *reinterpret_cast<const float4*>(&As[(ty * 4 + i) * AS_STRIDE + k0]);
                a[i][0] = v.x; a[i][1] = v.y; a[i][2] = v.z; a[i][3] = v.w;
            }
#pragma unroll
            for (int kk = 0; kk < 4; ++kk) {
                float bv[8];
#pragma unroll
                for (int jj = 0; jj < 8; ++jj) bv[jj] = Bs[(k0 + kk) * BS_STRIDE + tx + 16 * jj];
#pragma unroll
                for (int i = 0; i < 4; ++i)
#pragma unroll
                    for (int jj = 0; jj < 8; ++jj) acc[i][jj] += a[i][kk] * bv[jj];
            }
        }
        __syncthreads();
    }
    float bv[8];
#pragma unroll
    for (int jj = 0; jj < 8; ++jj) bv[jj] = bias[tx + 16 * jj];
#pragma unroll
    for (int i = 0; i < 4; ++i) {
        int n = node0 + ty * 4 + i;
        if (n < N) {
            float* o = out + (size_t)n * D;
#pragma unroll
            for (int jj = 0; jj < 8; ++jj) {
                float v = acc[i][jj] + bv[jj];
                o[tx + 16 * jj] = v > 0.0f ? v : 0.0f;
            }
        }
    }
}

extern "C" void kernel_launch(void* const* d_in, const int* in_sizes, int n_in,
                              void* d_out, int out_size, void* d_ws, size_t ws_size,
                              hipStream_t stream) {
    const float* feat = (const float*)d_in[0];
    const int*   src  = (const int*)d_in[1];
    const int*   dst  = (const int*)d_in[2];
    const float* w    = (const float*)d_in[3];
    const float* Wm   = (const float*)d_in[4];
    const float* bias = (const float*)d_in[5];
    float* out = (float*)d_out;

    const int N = in_sizes[0] / D;   // 50000
    const int E = in_sizes[1];       // 800000

    const size_t ep_b  = (size_t)N * CAP * 4;       // packed plane-major CSR, 12.8 MB
    const size_t cnt_b = (size_t)N * sizeof(int);
    const size_t tf_b  = (size_t)N * D * 2;         // column-blocked bf16 tf
    auto align_up = [](size_t x) { return (x + 255) & ~(size_t)255; };

    const size_t need_full = align_up(ep_b) + align_up(cnt_b) + align_up(tf_b);

    // fast path needs: src ids fit in 16 bits, padded-CSR tail safe, ws fits
    if (ws_size >= need_full && N <= 65536 &&
        (long long)E <= (long long)N * (CAP / 4)) {
        char* p = (char*)d_ws;
        unsigned* ep  = (unsigned*)p;  p += align_up(ep_b);
        int*      cnt = (int*)p;       p += align_up(cnt_b);
        unsigned short* tf = (unsigned short*)p;

        (void)hipMemsetAsync(cnt, 0, cnt_b, stream);
        gemm_bucket<<<GEMM_BLOCKS, 256, 0, stream>>>(
            feat, Wm, tf, src, dst, w, cnt, ep, N, E);
        csr_gather_cb<<<((N + 127) / 128) * 8, 256, 0, stream>>>(tf, ep, cnt, bias, out, N);
    } else {
        // fallback: atomic scatter into out, then in-place fp32 linear
        (void)hipMemsetAsync(out, 0, (size_t)N * D * sizeof(float), stream);
        long long st = (long long)E * 32;
        edge_scatter<<<(int)((st + 255) / 256), 256, 0, stream>>>(feat, src, dst, w, out, E);
        node_linear<<<(N + TILE_M - 1) / TILE_M, 256, 0, stream>>>(out, Wm, bias, out, N);
    }
}

// Round 5
// 165.049 us; speedup vs baseline: 1.0577x; 1.0577x over previous
//
#include <hip/hip_runtime.h>

#define D 128
#define TILE_M 64
#define BS_STRIDE 129
#define AS_STRIDE 68
#define WS_STRIDE 136   // shorts; 272 B rows -> 16 B aligned, banks spread
#define DS_STRIDE 136
#define GEMM_BLOCKS 768     // == 256 CU x 3 blocks/CU (52 KB LDS) -> fully co-resident
#define BUCKET_BLOCKS 2048  // LDS-free, 8 blocks/CU -> full 32 waves/CU; %8==0 for XCD parity
#define CAP 64              // padded CSR row capacity (max degree ~35; 64 = 12 sigma)

typedef __attribute__((ext_vector_type(8))) short short8;
typedef __attribute__((ext_vector_type(4))) float floatx4;
typedef __attribute__((ext_vector_type(4))) unsigned short ushortx4;

__device__ __forceinline__ unsigned short f2bf(float f) {
    unsigned u = __float_as_uint(f);
    u += 0x7fffu + ((u >> 16) & 1u);   // round-to-nearest-even
    return (unsigned short)(u >> 16);
}

// ---------------- bucket: XCD-owned scatter into plane-major padded CSR ----------------
// r16 attribution experiment. r14's split bucket (46us) had NO XCD ownership: each
// plane-major ep line (16 adjacent dst at equal pos) was written by ~16 RANDOM XCDs ->
// per-4B-store cross-XCD exclusive-ownership transfers (coherence ping-pong), consistent
// with its 47MB WRITE_SIZE. This version keeps r2's dst-range ownership (blockIdx&7 =
// XCD, default round-robin dispatch): all cnt+ep traffic is XCD-local, per-XCD write
// set = 1.6MB ep slice + 25KB cnt slice (L2-resident), at FULL occupancy (no LDS,
// 8 blocks/CU). Cost: 8x replicated dst/src/w scan (76.8MB, L3-served, ~8us of BW).
// Pre-committed read: <=22us & WRITE ~20MB => coherence theory; ~45us & WRITE ~47MB =>
// intrinsic atomic wall -> next: LDS-staged appends.
// Edge record = 4B: [31:16] = bf16(w), [15:0] = src (needs N <= 65536).
__global__ __launch_bounds__(256) void bucket_xcd(
    const int* __restrict__ src, const int* __restrict__ dst,
    const float* __restrict__ w, int* __restrict__ cnt,
    unsigned* __restrict__ ep, int N, int E)
{
    const int xcd = blockIdx.x & 7;
    const int blk = blockIdx.x >> 3;
    const int nblk = BUCKET_BLOCKS >> 3;      // 256 blocks per XCD group
    const int lo = (int)((long long)xcd * N / 8);
    const int hi = (int)((long long)(xcd + 1) * N / 8);
    const int E4 = E & ~3;
    for (int e4 = (blk * 256 + threadIdx.x) * 4; e4 < E4; e4 += nblk * 256 * 4) {
        const int4   d4 = *reinterpret_cast<const int4*>(dst + e4);
        const int4   s4 = *reinterpret_cast<const int4*>(src + e4);
        const float4 w4 = *reinterpret_cast<const float4*>(w + e4);
#pragma unroll
        for (int j = 0; j < 4; ++j) {
            int d = (j == 0) ? d4.x : (j == 1) ? d4.y : (j == 2) ? d4.z : d4.w;
            if (d >= lo && d < hi) {
                int   sj = (j == 0) ? s4.x : (j == 1) ? s4.y : (j == 2) ? s4.z : s4.w;
                float wj = (j == 0) ? w4.x : (j == 1) ? w4.y : (j == 2) ? w4.z : w4.w;
                unsigned rec = ((unsigned)f2bf(wj) << 16) | (unsigned)sj;
                int pos = atomicAdd(&cnt[d], 1);
                if (pos < CAP)
                    ep[(size_t)pos * (size_t)N + (size_t)d] = rec;   // plane-major
            }
        }
    }
    // tail (E not multiple of 4): single thread, no ownership filter (tiny count)
    if (blockIdx.x == 0 && threadIdx.x == 0) {
        for (int e = E4; e < E; ++e) {
            int d = dst[e];
            unsigned rec = ((unsigned)f2bf(w[e]) << 16) | (unsigned)src[e];
            int pos = atomicAdd(&cnt[d], 1);
            if (pos < CAP)
                ep[(size_t)pos * (size_t)N + (size_t)d] = rec;
        }
    }
}

// ---------------- tf = bf16(feat @ W^T), MFMA (r2 phase-2 verbatim) ----------------
__global__ __launch_bounds__(256) void gemm_tf(
    const float* __restrict__ feat, const float* __restrict__ Wm,
    unsigned short* __restrict__ tf, int N)
{
    __shared__ unsigned short Ws[128 * WS_STRIDE];  // 34816 B
    __shared__ unsigned short Ds[64 * DS_STRIDE];   // 17408 B

    const int tid = threadIdx.x;
    for (int idx = tid; idx < 128 * 128 / 4; idx += 256) {
        int r = idx >> 5;
        int c = (idx & 31) * 4;
        const float4 v = reinterpret_cast<const float4*>(Wm)[idx];
        ushortx4 s;
        s[0] = f2bf(v.x); s[1] = f2bf(v.y); s[2] = f2bf(v.z); s[3] = f2bf(v.w);
        *reinterpret_cast<ushortx4*>(&Ws[r * WS_STRIDE + c]) = s;
    }
    __syncthreads();

    const int lane = tid & 63;
    const int wave = tid >> 6;
    const int kq = (lane >> 4) * 8;
    const int ntiles = (N + 63) >> 6;

    for (int t = blockIdx.x; t < ntiles; t += GEMM_BLOCKS) {
        const int node0 = t * 64;
        const int mr = node0 + wave * 16 + (lane & 15);
        const float* arow = feat + (size_t)(mr < N ? mr : (N - 1)) * D + kq;

        short8 a[4];
#pragma unroll
        for (int kt = 0; kt < 4; ++kt) {
            const float* p = arow + kt * 32;
            const float4 lo = *reinterpret_cast<const float4*>(p);
            const float4 hi = *reinterpret_cast<const float4*>(p + 4);
            short8 v;
            v[0] = (short)f2bf(lo.x); v[1] = (short)f2bf(lo.y);
            v[2] = (short)f2bf(lo.z); v[3] = (short)f2bf(lo.w);
            v[4] = (short)f2bf(hi.x); v[5] = (short)f2bf(hi.y);
            v[6] = (short)f2bf(hi.z); v[7] = (short)f2bf(hi.w);
            a[kt] = v;
        }

        floatx4 acc[8];
#pragma unroll
        for (int nt = 0; nt < 8; ++nt) {
            acc[nt][0] = 0.f; acc[nt][1] = 0.f; acc[nt][2] = 0.f; acc[nt][3] = 0.f;
        }
#pragma unroll
        for (int nt = 0; nt < 8; ++nt) {
            const unsigned short* brow = &Ws[(nt * 16 + (lane & 15)) * WS_STRIDE + kq];
#pragma unroll
            for (int kt = 0; kt < 4; ++kt) {
                short8 b = *reinterpret_cast<const short8*>(brow + kt * 32);
                acc[nt] = __builtin_amdgcn_mfma_f32_16x16x32_bf16(a[kt], b, acc[nt], 0, 0, 0);
            }
        }

        __syncthreads();   // prev tile's Ds readers done
        const int mlocal = wave * 16 + (lane >> 4) * 4;
        const int col = lane & 15;
#pragma unroll
        for (int r = 0; r < 4; ++r) {
            unsigned short* drow = &Ds[(mlocal + r) * DS_STRIDE + col];
#pragma unroll
            for (int nt = 0; nt < 8; ++nt)
                drow[nt * 16] = f2bf(acc[nt][r]);
        }
        __syncthreads();

        // 64 rows x 16 chunks of 16B; coalesced, row-major tf
        for (int idx = tid; idx < 64 * 16; idx += 256) {
            int row = idx >> 4;
            int chunk = idx & 15;
            int m = node0 + row;
            if (m < N) {
                uint4 v = *reinterpret_cast<const uint4*>(&Ds[row * DS_STRIDE + chunk * 8]);
                *reinterpret_cast<uint4*>(tf + (size_t)m * D + chunk * 8) = v;
            }
        }
    }
}

// ---------------- gather-reduce (r2 verbatim): out = relu(sum w*tf[src] + b) ----------------
// Plane-major ep: node's records sit at ep[p*N + node]. A block covers 16 contiguous
// nodes, so each plane's 16 records are ONE 64B line (N*4 is 64-divisible) shared by
// the block's 16 groups. 16 lanes per node, uint4 (16B = 8 bf16) per lane; 8 planes
// unrolled -> 8 independent tf-row loads in flight per lane (latency hiding).
__global__ __launch_bounds__(256) void csr_gather_bf16(
    const unsigned short* __restrict__ tf, const unsigned* __restrict__ ep,
    const int* __restrict__ cnt, const float* __restrict__ bias,
    float* __restrict__ out, int N)
{
    int node = blockIdx.x * 16 + (threadIdx.x >> 4);
    if (node >= N) return;
    const int lane = threadIdx.x & 15;
    const int c = lane << 3;               // 8 bf16 per lane
    const unsigned* col = ep + node;       // stride N per plane
    int end = cnt[node];
    end = end < CAP ? end : CAP;
    int p = 0;
    float a0 = 0.f, a1 = 0.f, a2 = 0.f, a3 = 0.f;
    float a4 = 0.f, a5 = 0.f, a6 = 0.f, a7 = 0.f;

#define ACC8(Q, W)                                       \
    a0 += __uint_as_float((Q).x << 16) * (W);            \
    a1 += __uint_as_float((Q).x & 0xffff0000u) * (W);    \
    a2 += __uint_as_float((Q).y << 16) * (W);            \
    a3 += __uint_as_float((Q).y & 0xffff0000u) * (W);    \
    a4 += __uint_as_float((Q).z << 16) * (W);            \
    a5 += __uint_as_float((Q).z & 0xffff0000u) * (W);    \
    a6 += __uint_as_float((Q).w << 16) * (W);            \
    a7 += __uint_as_float((Q).w & 0xffff0000u) * (W);

    for (; p + 7 < end; p += 8) {
        unsigned r[8];
#pragma unroll
        for (int j = 0; j < 8; ++j) r[j] = col[(size_t)(p + j) * N];
        uint4 q[8];
        float wv[8];
#pragma unroll
        for (int j = 0; j < 8; ++j) {
            q[j] = *reinterpret_cast<const uint4*>(tf + (size_t)(r[j] & 0xffffu) * D + c);
            wv[j] = __uint_as_float(r[j] & 0xffff0000u);
        }
#pragma unroll
        for (int j = 0; j < 8; ++j) { ACC8(q[j], wv[j]) }
    }
    for (; p + 3 < end; p += 4) {
        unsigned r[4];
#pragma unroll
        for (int j = 0; j < 4; ++j) r[j] = col[(size_t)(p + j) * N];
        uint4 q[4];
        float wv[4];
#pragma unroll
        for (int j = 0; j < 4; ++j) {
            q[j] = *reinterpret_cast<const uint4*>(tf + (size_t)(r[j] & 0xffffu) * D + c);
            wv[j] = __uint_as_float(r[j] & 0xffff0000u);
        }
#pragma unroll
        for (int j = 0; j < 4; ++j) { ACC8(q[j], wv[j]) }
    }
    for (; p < end; ++p) {
        unsigned r = col[(size_t)p * N];
        float wv = __uint_as_float(r & 0xffff0000u);
        uint4 q = *reinterpret_cast<const uint4*>(tf + (size_t)(r & 0xffffu) * D + c);
        ACC8(q, wv)
    }
#undef ACC8

    const float4 bv0 = *reinterpret_cast<const float4*>(bias + c);
    const float4 bv1 = *reinterpret_cast<const float4*>(bias + c + 4);
    float4 r0, r1;
    r0.x = fmaxf(a0 + bv0.x, 0.f);
    r0.y = fmaxf(a1 + bv0.y, 0.f);
    r0.z = fmaxf(a2 + bv0.z, 0.f);
    r0.w = fmaxf(a3 + bv0.w, 0.f);
    r1.x = fmaxf(a4 + bv1.x, 0.f);
    r1.y = fmaxf(a5 + bv1.y, 0.f);
    r1.z = fmaxf(a6 + bv1.z, 0.f);
    r1.w = fmaxf(a7 + bv1.w, 0.f);
    float* o = out + (size_t)node * D + c;
    *reinterpret_cast<float4*>(o) = r0;
    *reinterpret_cast<float4*>(o + 4) = r1;
}

// ---------------- tier-1 fallback: atomic scatter + fp32 GEMM ----------------
__global__ __launch_bounds__(256) void edge_scatter(
    const float* __restrict__ feat, const int* __restrict__ src,
    const int* __restrict__ dst, const float* __restrict__ w,
    float* __restrict__ agg, int E)
{
    long long idx = (long long)blockIdx.x * 256 + threadIdx.x;
    int e = (int)(idx >> 5);
    if (e >= E) return;
    int c = ((int)idx & 31) << 2;
    int s = src[e];
    int d = dst[e];
    float wv = w[e];
    const float4 f = *reinterpret_cast<const float4*>(feat + (size_t)s * D + c);
    float* a = agg + (size_t)d * D + c;
    atomicAdd(a + 0, f.x * wv);
    atomicAdd(a + 1, f.y * wv);
    atomicAdd(a + 2, f.z * wv);
    atomicAdd(a + 3, f.w * wv);
}

__global__ __launch_bounds__(256) void node_linear(
    const float* __restrict__ in, const float* __restrict__ Wm,
    const float* __restrict__ bias, float* __restrict__ out, int N)
{
    __shared__ float Bs[64 * BS_STRIDE];
    __shared__ float As[TILE_M * AS_STRIDE];
    const int tid = threadIdx.x;
    const int tx = tid & 15;
    const int ty = tid >> 4;
    const int node0 = blockIdx.x * TILE_M;
    float acc[4][8];
#pragma unroll
    for (int i = 0; i < 4; ++i)
#pragma unroll
        for (int jj = 0; jj < 8; ++jj) acc[i][jj] = 0.0f;
    for (int kh = 0; kh < 2; ++kh) {
        const int kbase = kh * 64;
        for (int i = tid; i < 128 * 64; i += 256) {
            int j = i >> 6, k = i & 63;
            Bs[k * BS_STRIDE + j] = Wm[j * 128 + kbase + k];
        }
        for (int i = tid; i < TILE_M * 64; i += 256) {
            int m = i >> 6, k = i & 63;
            int n = node0 + m;
            As[m * AS_STRIDE + k] = (n < N) ? in[(size_t)n * D + kbase + k] : 0.0f;
        }
        __syncthreads();
        for (int k0 = 0; k0 < 64; k0 += 4) {
            float a[4][4];
#pragma unroll
            for (int i = 0; i < 4; ++i) {
                const float4 v = *reinterpret_cast<const float4*>(&As[(ty * 4 + i) * AS_STRIDE + k0]);
                a[i][0] = v.x; a[i][1] = v.y; a[i][2] = v.z; a[i][3] = v.w;
            }
#pragma unroll
            for (int kk = 0; kk < 4; ++kk) {
                float bv[8];
#pragma unroll
                for (int jj = 0; jj < 8; ++jj) bv[jj] = Bs[(k0 + kk) * BS_STRIDE + tx + 16 * jj];
#pragma unroll
                for (int i = 0; i < 4; ++i)
#pragma unroll
                    for (int jj = 0; jj < 8; ++jj) acc[i][jj] += a[i][kk] * bv[jj];
            }
        }
        __syncthreads();
    }
    float bv[8];
#pragma unroll
    for (int jj = 0; jj < 8; ++jj) bv[jj] = bias[tx + 16 * jj];
#pragma unroll
    for (int i = 0; i < 4; ++i) {
        int n = node0 + ty * 4 + i;
        if (n < N) {
            float* o = out + (size_t)n * D;
#pragma unroll
            for (int jj = 0; jj < 8; ++jj) {
                float v = acc[i][jj] + bv[jj];
                o[tx + 16 * jj] = v > 0.0f ? v : 0.0f;
            }
        }
    }
}

extern "C" void kernel_launch(void* const* d_in, const int* in_sizes, int n_in,
                              void* d_out, int out_size, void* d_ws, size_t ws_size,
                              hipStream_t stream) {
    const float* feat = (const float*)d_in[0];
    const int*   src  = (const int*)d_in[1];
    const int*   dst  = (const int*)d_in[2];
    const float* w    = (const float*)d_in[3];
    const float* Wm   = (const float*)d_in[4];
    const float* bias = (const float*)d_in[5];
    float* out = (float*)d_out;

    const int N = in_sizes[0] / D;   // 50000
    const int E = in_sizes[1];       // 800000

    const size_t ep_b  = (size_t)N * CAP * 4;       // packed plane-major CSR, 12.8 MB
    const size_t cnt_b = (size_t)N * sizeof(int);
    const size_t tf_b  = (size_t)N * D * 2;
    auto align_up = [](size_t x) { return (x + 255) & ~(size_t)255; };

    const size_t need_full = align_up(ep_b) + align_up(cnt_b) + align_up(tf_b);

    // fast path needs: src ids fit in 16 bits, padded-CSR tail safe, ws fits
    if (ws_size >= need_full && N <= 65536 &&
        (long long)E <= (long long)N * (CAP / 4)) {
        char* p = (char*)d_ws;
        unsigned* ep  = (unsigned*)p;  p += align_up(ep_b);
        int*      cnt = (int*)p;       p += align_up(cnt_b);
        unsigned short* tf = (unsigned short*)p;

        (void)hipMemsetAsync(cnt, 0, cnt_b, stream);
        bucket_xcd<<<BUCKET_BLOCKS, 256, 0, stream>>>(src, dst, w, cnt, ep, N, E);
        gemm_tf<<<GEMM_BLOCKS, 256, 0, stream>>>(feat, Wm, tf, N);
        csr_gather_bf16<<<(N + 15) / 16, 256, 0, stream>>>(tf, ep, cnt, bias, out, N);
    } else {
        // fallback: atomic scatter into out, then in-place fp32 linear
        (void)hipMemsetAsync(out, 0, (size_t)N * D * sizeof(float), stream);
        long long st = (long long)E * 32;
        edge_scatter<<<(int)((st + 255) / 256), 256, 0, stream>>>(feat, src, dst, w, out, E);
        node_linear<<<(N + TILE_M - 1) / TILE_M, 256, 0, stream>>>(out, Wm, bias, out, N);
    }
}

// Round 6
// 160.670 us; speedup vs baseline: 1.0865x; 1.0273x over previous
//
#include <hip/hip_runtime.h>

#define D 128
#define TILE_M 64
#define BS_STRIDE 129
#define AS_STRIDE 68
#define WS_STRIDE 136   // shorts; 272 B rows -> 16 B aligned, banks spread
#define DS_STRIDE 136
#define GEMM_BLOCKS 768     // == 256 CU x 3 blocks/CU (52 KB LDS) -> fully co-resident
#define CAP 64              // padded CSR row capacity (max degree ~35; 64 = 12 sigma)
#define CSH 9               // coarse bin = dst>>9 (512 nodes/bin); N<=65536 -> <=128 bins
#define CBCAP 16384         // coarse-bin capacity (mean 8163 @ E=800K, ~45 sigma slack)
#define P1_BLOCKS 256
#define P1_CHUNK_MAX 3200   // LDS grouped[] capacity -> requires E <= 256*3200

typedef __attribute__((ext_vector_type(8))) short short8;
typedef __attribute__((ext_vector_type(4))) float floatx4;
typedef __attribute__((ext_vector_type(4))) unsigned short ushortx4;

__device__ __forceinline__ unsigned short f2bf(float f) {
    unsigned u = __float_as_uint(f);
    u += 0x7fffu + ((u >> 16) & 1u);   // round-to-nearest-even
    return (unsigned short)(u >> 16);
}

// ---------------- pass 1: LDS radix partition of edges into coarse dst-bins ----------------
// r17: the per-edge global scatter is dead (r14/r16: ~45us at ANY occupancy/layout/
// placement -> 800K device-scope returning atomics + 800K 4B scattered stores ARE the
// wall, ~17 atomics/ns chip-wide). This kernel replaces them: LDS histogram over
// ncb=98 coarse bins, thread-0 exclusive scan, ONE global atomicAdd per (block,bin)
// (25K total, each amortized over ~32 edges), LDS re-grouping, then contiguous run
// flush (avg 32 edges = 256B per run). Record in binned[] = uint2{dst, bf16(w)<<16|src}.
__global__ __launch_bounds__(256) void edge_partition(
    const int* __restrict__ src, const int* __restrict__ dst,
    const float* __restrict__ w, int* __restrict__ gcnt,
    uint2* __restrict__ binned, int N, int E)
{
    __shared__ int hist[128], startb[128], cursor[128], gbase[128];
    __shared__ uint2 grouped[P1_CHUNK_MAX];   // 25.6 KB
    const int tid = threadIdx.x;
    const int ncb = (N + 511) >> CSH;
    const int chunk = (E + P1_BLOCKS - 1) / P1_BLOCKS;   // 3125 @ E=800000
    const int base = blockIdx.x * chunk;
    const int lim = (E - base) < chunk ? (E - base) : chunk;   // may be <=0

    if (tid < 128) hist[tid] = 0;
    __syncthreads();
    // sweep 1: histogram (dst scan, coalesced 4B/lane)
    for (int i = tid; i < lim; i += 256)
        atomicAdd(&hist[dst[base + i] >> CSH], 1);
    __syncthreads();
    if (tid == 0) {
        int s = 0;
        for (int b = 0; b < ncb; ++b) { startb[b] = s; s += hist[b]; }
    }
    __syncthreads();
    if (tid < ncb) {
        gbase[tid]  = atomicAdd(&gcnt[tid], hist[tid]);   // the ONLY global atomics
        cursor[tid] = startb[tid];
    }
    __syncthreads();
    // sweep 2: place into LDS grouped order
    for (int i = tid; i < lim; i += 256) {
        int e = base + i;
        int d = dst[e];
        unsigned rec = ((unsigned)f2bf(w[e]) << 16) | (unsigned)src[e];
        int g = atomicAdd(&cursor[d >> CSH], 1);
        grouped[g] = make_uint2((unsigned)d, rec);
    }
    __syncthreads();
    // flush: contiguous per-bin runs to global
    for (int i = tid; i < lim; i += 256) {
        uint2 v = grouped[i];
        int b = (int)(v.x >> CSH);
        int off = gbase[b] + (i - startb[b]);
        if (off < CBCAP)
            binned[(size_t)b * CBCAP + (size_t)off] = v;
    }
}

// ---------------- pass 2: build plane-major padded CSR from coarse bins ----------------
// One block per 128-node FINE bin (fb = d>>7); reads its coarse bin's edge list
// (cb = fb>>2, 4x filter amplification but L2/L3-warm), slots via LDS atomics into
// rowsT[pos][node] (transposed -> conflict-free coalesced flush), writes ep planes
// as 512B contiguous runs and cnt[] directly (no cnt memset needed anywhere).
__global__ __launch_bounds__(256) void csr_from_bins(
    const uint2* __restrict__ binned, const int* __restrict__ gcnt,
    unsigned* __restrict__ ep, int* __restrict__ cnt, int N)
{
    __shared__ unsigned rowsT[CAP * 128];   // 32 KB
    __shared__ int lcnt[128];
    __shared__ int maxc;
    const int tid = threadIdx.x;
    const int fb = blockIdx.x;
    const int d0 = fb << 7;
    const int cb = fb >> 2;

    if (tid < 128) lcnt[tid] = 0;
    __syncthreads();
    int len = gcnt[cb];
    len = len < CBCAP ? len : CBCAP;
    const uint2* bp = binned + (size_t)cb * CBCAP;
    for (int i = tid; i < len; i += 256) {
        uint2 v = bp[i];
        int d = (int)v.x;
        if ((d >> 7) == fb) {
            int pos = atomicAdd(&lcnt[d & 127], 1);
            if (pos < CAP) rowsT[pos * 128 + (d & 127)] = v.y;
        }
    }
    __syncthreads();
    if (tid == 0) {
        int m = 0;
        for (int j = 0; j < 128; ++j) m = m > lcnt[j] ? m : lcnt[j];
        maxc = m < CAP ? m : CAP;
    }
    __syncthreads();
    const int pu = maxc;
    for (int idx = tid; idx < (pu << 7); idx += 256) {
        int p = idx >> 7, j = idx & 127;
        int d = d0 + j;
        if (d < N) ep[(size_t)p * N + d] = rowsT[idx];   // 512B runs, coalesced
    }
    if (tid < 128) {
        int d = d0 + tid;
        if (d < N) cnt[d] = lcnt[tid];
    }
}

// ---------------- tf = bf16(feat @ W^T), MFMA (unchanged, proven) ----------------
__global__ __launch_bounds__(256) void gemm_tf(
    const float* __restrict__ feat, const float* __restrict__ Wm,
    unsigned short* __restrict__ tf, int N)
{
    __shared__ unsigned short Ws[128 * WS_STRIDE];  // 34816 B
    __shared__ unsigned short Ds[64 * DS_STRIDE];   // 17408 B

    const int tid = threadIdx.x;
    for (int idx = tid; idx < 128 * 128 / 4; idx += 256) {
        int r = idx >> 5;
        int c = (idx & 31) * 4;
        const float4 v = reinterpret_cast<const float4*>(Wm)[idx];
        ushortx4 s;
        s[0] = f2bf(v.x); s[1] = f2bf(v.y); s[2] = f2bf(v.z); s[3] = f2bf(v.w);
        *reinterpret_cast<ushortx4*>(&Ws[r * WS_STRIDE + c]) = s;
    }
    __syncthreads();

    const int lane = tid & 63;
    const int wave = tid >> 6;
    const int kq = (lane >> 4) * 8;
    const int ntiles = (N + 63) >> 6;

    for (int t = blockIdx.x; t < ntiles; t += GEMM_BLOCKS) {
        const int node0 = t * 64;
        const int mr = node0 + wave * 16 + (lane & 15);
        const float* arow = feat + (size_t)(mr < N ? mr : (N - 1)) * D + kq;

        short8 a[4];
#pragma unroll
        for (int kt = 0; kt < 4; ++kt) {
            const float* p = arow + kt * 32;
            const float4 lo = *reinterpret_cast<const float4*>(p);
            const float4 hi = *reinterpret_cast<const float4*>(p + 4);
            short8 v;
            v[0] = (short)f2bf(lo.x); v[1] = (short)f2bf(lo.y);
            v[2] = (short)f2bf(lo.z); v[3] = (short)f2bf(lo.w);
            v[4] = (short)f2bf(hi.x); v[5] = (short)f2bf(hi.y);
            v[6] = (short)f2bf(hi.z); v[7] = (short)f2bf(hi.w);
            a[kt] = v;
        }

        floatx4 acc[8];
#pragma unroll
        for (int nt = 0; nt < 8; ++nt) {
            acc[nt][0] = 0.f; acc[nt][1] = 0.f; acc[nt][2] = 0.f; acc[nt][3] = 0.f;
        }
#pragma unroll
        for (int nt = 0; nt < 8; ++nt) {
            const unsigned short* brow = &Ws[(nt * 16 + (lane & 15)) * WS_STRIDE + kq];
#pragma unroll
            for (int kt = 0; kt < 4; ++kt) {
                short8 b = *reinterpret_cast<const short8*>(brow + kt * 32);
                acc[nt] = __builtin_amdgcn_mfma_f32_16x16x32_bf16(a[kt], b, acc[nt], 0, 0, 0);
            }
        }

        __syncthreads();   // prev tile's Ds readers done
        const int mlocal = wave * 16 + (lane >> 4) * 4;
        const int col = lane & 15;
#pragma unroll
        for (int r = 0; r < 4; ++r) {
            unsigned short* drow = &Ds[(mlocal + r) * DS_STRIDE + col];
#pragma unroll
            for (int nt = 0; nt < 8; ++nt)
                drow[nt * 16] = f2bf(acc[nt][r]);
        }
        __syncthreads();

        // 64 rows x 16 chunks of 16B; coalesced, row-major tf
        for (int idx = tid; idx < 64 * 16; idx += 256) {
            int row = idx >> 4;
            int chunk = idx & 15;
            int m = node0 + row;
            if (m < N) {
                uint4 v = *reinterpret_cast<const uint4*>(&Ds[row * DS_STRIDE + chunk * 8]);
                *reinterpret_cast<uint4*>(tf + (size_t)m * D + chunk * 8) = v;
            }
        }
    }
}

// ---------------- gather-reduce (unchanged, proven): out = relu(sum w*tf[src] + b) ----------------
__global__ __launch_bounds__(256) void csr_gather_bf16(
    const unsigned short* __restrict__ tf, const unsigned* __restrict__ ep,
    const int* __restrict__ cnt, const float* __restrict__ bias,
    float* __restrict__ out, int N)
{
    int node = blockIdx.x * 16 + (threadIdx.x >> 4);
    if (node >= N) return;
    const int lane = threadIdx.x & 15;
    const int c = lane << 3;               // 8 bf16 per lane
    const unsigned* col = ep + node;       // stride N per plane
    int end = cnt[node];
    end = end < CAP ? end : CAP;
    int p = 0;
    float a0 = 0.f, a1 = 0.f, a2 = 0.f, a3 = 0.f;
    float a4 = 0.f, a5 = 0.f, a6 = 0.f, a7 = 0.f;

#define ACC8(Q, W)                                       \
    a0 += __uint_as_float((Q).x << 16) * (W);            \
    a1 += __uint_as_float((Q).x & 0xffff0000u) * (W);    \
    a2 += __uint_as_float((Q).y << 16) * (W);            \
    a3 += __uint_as_float((Q).y & 0xffff0000u) * (W);    \
    a4 += __uint_as_float((Q).z << 16) * (W);            \
    a5 += __uint_as_float((Q).z & 0xffff0000u) * (W);    \
    a6 += __uint_as_float((Q).w << 16) * (W);            \
    a7 += __uint_as_float((Q).w & 0xffff0000u) * (W);

    for (; p + 7 < end; p += 8) {
        unsigned r[8];
#pragma unroll
        for (int j = 0; j < 8; ++j) r[j] = col[(size_t)(p + j) * N];
        uint4 q[8];
        float wv[8];
#pragma unroll
        for (int j = 0; j < 8; ++j) {
            q[j] = *reinterpret_cast<const uint4*>(tf + (size_t)(r[j] & 0xffffu) * D + c);
            wv[j] = __uint_as_float(r[j] & 0xffff0000u);
        }
#pragma unroll
        for (int j = 0; j < 8; ++j) { ACC8(q[j], wv[j]) }
    }
    for (; p + 3 < end; p += 4) {
        unsigned r[4];
#pragma unroll
        for (int j = 0; j < 4; ++j) r[j] = col[(size_t)(p + j) * N];
        uint4 q[4];
        float wv[4];
#pragma unroll
        for (int j = 0; j < 4; ++j) {
            q[j] = *reinterpret_cast<const uint4*>(tf + (size_t)(r[j] & 0xffffu) * D + c);
            wv[j] = __uint_as_float(r[j] & 0xffff0000u);
        }
#pragma unroll
        for (int j = 0; j < 4; ++j) { ACC8(q[j], wv[j]) }
    }
    for (; p < end; ++p) {
        unsigned r = col[(size_t)p * N];
        float wv = __uint_as_float(r & 0xffff0000u);
        uint4 q = *reinterpret_cast<const uint4*>(tf + (size_t)(r & 0xffffu) * D + c);
        ACC8(q, wv)
    }
#undef ACC8

    const float4 bv0 = *reinterpret_cast<const float4*>(bias + c);
    const float4 bv1 = *reinterpret_cast<const float4*>(bias + c + 4);
    float4 r0, r1;
    r0.x = fmaxf(a0 + bv0.x, 0.f);
    r0.y = fmaxf(a1 + bv0.y, 0.f);
    r0.z = fmaxf(a2 + bv0.z, 0.f);
    r0.w = fmaxf(a3 + bv0.w, 0.f);
    r1.x = fmaxf(a4 + bv1.x, 0.f);
    r1.y = fmaxf(a5 + bv1.y, 0.f);
    r1.z = fmaxf(a6 + bv1.z, 0.f);
    r1.w = fmaxf(a7 + bv1.w, 0.f);
    float* o = out + (size_t)node * D + c;
    *reinterpret_cast<float4*>(o) = r0;
    *reinterpret_cast<float4*>(o + 4) = r1;
}

// ---------------- tier-1 fallback: atomic scatter + fp32 GEMM ----------------
__global__ __launch_bounds__(256) void edge_scatter(
    const float* __restrict__ feat, const int* __restrict__ src,
    const int* __restrict__ dst, const float* __restrict__ w,
    float* __restrict__ agg, int E)
{
    long long idx = (long long)blockIdx.x * 256 + threadIdx.x;
    int e = (int)(idx >> 5);
    if (e >= E) return;
    int c = ((int)idx & 31) << 2;
    int s = src[e];
    int d = dst[e];
    float wv = w[e];
    const float4 f = *reinterpret_cast<const float4*>(feat + (size_t)s * D + c);
    float* a = agg + (size_t)d * D + c;
    atomicAdd(a + 0, f.x * wv);
    atomicAdd(a + 1, f.y * wv);
    atomicAdd(a + 2, f.z * wv);
    atomicAdd(a + 3, f.w * wv);
}

__global__ __launch_bounds__(256) void node_linear(
    const float* __restrict__ in, const float* __restrict__ Wm,
    const float* __restrict__ bias, float* __restrict__ out, int N)
{
    __shared__ float Bs[64 * BS_STRIDE];
    __shared__ float As[TILE_M * AS_STRIDE];
    const int tid = threadIdx.x;
    const int tx = tid & 15;
    const int ty = tid >> 4;
    const int node0 = blockIdx.x * TILE_M;
    float acc[4][8];
#pragma unroll
    for (int i = 0; i < 4; ++i)
#pragma unroll
        for (int jj = 0; jj < 8; ++jj) acc[i][jj] = 0.0f;
    for (int kh = 0; kh < 2; ++kh) {
        const int kbase = kh * 64;
        for (int i = tid; i < 128 * 64; i += 256) {
            int j = i >> 6, k = i & 63;
            Bs[k * BS_STRIDE + j] = Wm[j * 128 + kbase + k];
        }
        for (int i = tid; i < TILE_M * 64; i += 256) {
            int m = i >> 6, k = i & 63;
            int n = node0 + m;
            As[m * AS_STRIDE + k] = (n < N) ? in[(size_t)n * D + kbase + k] : 0.0f;
        }
        __syncthreads();
        for (int k0 = 0; k0 < 64; k0 += 4) {
            float a[4][4];
#pragma unroll
            for (int i = 0; i < 4; ++i) {
                const float4 v = *reinterpret_cast<const float4*>(&As[(ty * 4 + i) * AS_STRIDE + k0]);
                a[i][0] = v.x; a[i][1] = v.y; a[i][2] = v.z; a[i][3] = v.w;
            }
#pragma unroll
            for (int kk = 0; kk < 4; ++kk) {
                float bv[8];
#pragma unroll
                for (int jj = 0; jj < 8; ++jj) bv[jj] = Bs[(k0 + kk) * BS_STRIDE + tx + 16 * jj];
#pragma unroll
                for (int i = 0; i < 4; ++i)
#pragma unroll
                    for (int jj = 0; jj < 8; ++jj) acc[i][jj] += a[i][kk] * bv[jj];
            }
        }
        __syncthreads();
    }
    float bv[8];
#pragma unroll
    for (int jj = 0; jj < 8; ++jj) bv[jj] = bias[tx + 16 * jj];
#pragma unroll
    for (int i = 0; i < 4; ++i) {
        int n = node0 + ty * 4 + i;
        if (n < N) {
            float* o = out + (size_t)n * D;
#pragma unroll
            for (int jj = 0; jj < 8; ++jj) {
                float v = acc[i][jj] + bv[jj];
                o[tx + 16 * jj] = v > 0.0f ? v : 0.0f;
            }
        }
    }
}

extern "C" void kernel_launch(void* const* d_in, const int* in_sizes, int n_in,
                              void* d_out, int out_size, void* d_ws, size_t ws_size,
                              hipStream_t stream) {
    const float* feat = (const float*)d_in[0];
    const int*   src  = (const int*)d_in[1];
    const int*   dst  = (const int*)d_in[2];
    const float* w    = (const float*)d_in[3];
    const float* Wm   = (const float*)d_in[4];
    const float* bias = (const float*)d_in[5];
    float* out = (float*)d_out;

    const int N = in_sizes[0] / D;   // 50000
    const int E = in_sizes[1];       // 800000

    const int ncb = (N + 511) >> CSH;      // coarse bins (98)
    const int nfb = (N + 127) >> 7;        // fine bins   (391)

    const size_t ep_b     = (size_t)N * CAP * 4;              // plane-major CSR, 12.8 MB
    const size_t cnt_b    = (size_t)N * sizeof(int);
    const size_t tf_b     = (size_t)N * D * 2;
    const size_t binned_b = (size_t)ncb * CBCAP * sizeof(uint2);  // 12.8 MB
    const size_t gcnt_b   = 128 * sizeof(int);
    auto align_up = [](size_t x) { return (x + 255) & ~(size_t)255; };

    const size_t need_full = align_up(ep_b) + align_up(cnt_b) + align_up(tf_b) +
                             align_up(binned_b) + align_up(gcnt_b);

    // fast path: src ids fit 16 bits, pass-1 LDS chunk fits, padded-CSR sane, ws fits
    if (ws_size >= need_full && N <= 65536 &&
        E <= P1_BLOCKS * P1_CHUNK_MAX &&
        (long long)E <= (long long)N * (CAP / 4)) {
        char* p = (char*)d_ws;
        unsigned* ep     = (unsigned*)p;       p += align_up(ep_b);
        int*      cnt    = (int*)p;            p += align_up(cnt_b);
        unsigned short* tf = (unsigned short*)p; p += align_up(tf_b);
        uint2*    binned = (uint2*)p;          p += align_up(binned_b);
        int*      gcnt   = (int*)p;

        (void)hipMemsetAsync(gcnt, 0, gcnt_b, stream);   // only 512 B now
        edge_partition<<<P1_BLOCKS, 256, 0, stream>>>(src, dst, w, gcnt, binned, N, E);
        csr_from_bins<<<nfb, 256, 0, stream>>>(binned, gcnt, ep, cnt, N);
        gemm_tf<<<GEMM_BLOCKS, 256, 0, stream>>>(feat, Wm, tf, N);
        csr_gather_bf16<<<(N + 15) / 16, 256, 0, stream>>>(tf, ep, cnt, bias, out, N);
    } else {
        // fallback: atomic scatter into out, then in-place fp32 linear
        (void)hipMemsetAsync(out, 0, (size_t)N * D * sizeof(float), stream);
        long long st = (long long)E * 32;
        edge_scatter<<<(int)((st + 255) / 256), 256, 0, stream>>>(feat, src, dst, w, out, E);
        node_linear<<<(N + TILE_M - 1) / TILE_M, 256, 0, stream>>>(out, Wm, bias, out, N);
    }
}

// Round 7
// 147.529 us; speedup vs baseline: 1.1833x; 1.0891x over previous
//
#include <hip/hip_runtime.h>

#define D 128
#define TILE_M 64
#define BS_STRIDE 129
#define AS_STRIDE 68
#define WS_STRIDE 136   // shorts; 272 B rows -> 16 B aligned, banks spread
#define DS_STRIDE 136
#define GEMM_BLOCKS 768     // gemm role count in fused kernel (3 blocks/CU co-resident)
#define CAP 64              // padded CSR row capacity (max degree ~35; 64 = 12 sigma)
#define CSH 9               // coarse bin = dst>>9 (512 nodes/bin); N<=65536 -> <=128 bins
#define CBCAP 16384         // coarse-bin capacity (mean 8163 @ E=800K, ~45 sigma slack)
#define P1_BLOCKS 512       // 2 blocks/CU resident (14.6 KB LDS) -> 8 waves/CU
#define P1_CHUNK 1564       // ceil(E/P1_BLOCKS) rounded to x4; E <= 512*1564 = 800768

typedef __attribute__((ext_vector_type(8))) short short8;
typedef __attribute__((ext_vector_type(4))) float floatx4;
typedef __attribute__((ext_vector_type(4))) unsigned short ushortx4;

__device__ __forceinline__ unsigned short f2bf(float f) {
    unsigned u = __float_as_uint(f);
    u += 0x7fffu + ((u >> 16) & 1u);   // round-to-nearest-even
    return (unsigned short)(u >> 16);
}

// ---------------- pass 1: LDS radix partition of edges into coarse dst-bins ----------------
// r18 fix of r17's occupancy disease: 256 blocks was 1 block/CU, 4 waves/CU on a
// three-sweep latency-chain kernel (~13 serial load iters/sweep). Now 512 blocks
// (2/CU, 8 waves/CU) x int4 (4 edges/thread/iter) -> <=2 vector iterations per sweep.
// Global atomics: 512 blocks x 98 bins = 50K on 98 hot addresses, issued 98-parallel
// per block, amortized over ~16 edges each. Record = uint2{dst, bf16(w)<<16|src}.
__global__ __launch_bounds__(256) void edge_partition(
    const int* __restrict__ src, const int* __restrict__ dst,
    const float* __restrict__ w, int* __restrict__ gcnt,
    uint2* __restrict__ binned, int N, int E)
{
    __shared__ int hist[128], startb[128], cursor[128], gbase[128];
    __shared__ uint2 grouped[P1_CHUNK];   // 12512 B
    const int tid = threadIdx.x;
    const int ncb = (N + 511) >> CSH;
    const int base = blockIdx.x * P1_CHUNK;
    int lim = E - base;
    if (lim > P1_CHUNK) lim = P1_CHUNK;
    if (lim < 0) lim = 0;
    const int lim4 = lim & ~3;

    if (tid < 128) hist[tid] = 0;
    __syncthreads();
    // sweep 1: histogram (int4 dst scan)
    for (int i = tid * 4; i < lim4; i += 1024) {
        const int4 d4 = *reinterpret_cast<const int4*>(dst + base + i);
        atomicAdd(&hist[d4.x >> CSH], 1);
        atomicAdd(&hist[d4.y >> CSH], 1);
        atomicAdd(&hist[d4.z >> CSH], 1);
        atomicAdd(&hist[d4.w >> CSH], 1);
    }
    for (int i = lim4 + tid; i < lim; i += 256)
        atomicAdd(&hist[dst[base + i] >> CSH], 1);
    __syncthreads();
    if (tid == 0) {
        int s = 0;
        for (int b = 0; b < ncb; ++b) { startb[b] = s; s += hist[b]; }
    }
    __syncthreads();
    if (tid < ncb) {
        gbase[tid]  = atomicAdd(&gcnt[tid], hist[tid]);   // only global atomics
        cursor[tid] = startb[tid];
    }
    __syncthreads();
    // sweep 2: place into LDS grouped order (int4)
    for (int i = tid * 4; i < lim4; i += 1024) {
        const int4   d4 = *reinterpret_cast<const int4*>(dst + base + i);
        const int4   s4 = *reinterpret_cast<const int4*>(src + base + i);
        const float4 w4 = *reinterpret_cast<const float4*>(w + base + i);
#pragma unroll
        for (int j = 0; j < 4; ++j) {
            int   d  = (j == 0) ? d4.x : (j == 1) ? d4.y : (j == 2) ? d4.z : d4.w;
            int   sj = (j == 0) ? s4.x : (j == 1) ? s4.y : (j == 2) ? s4.z : s4.w;
            float wj = (j == 0) ? w4.x : (j == 1) ? w4.y : (j == 2) ? w4.z : w4.w;
            unsigned rec = ((unsigned)f2bf(wj) << 16) | (unsigned)sj;
            int g = atomicAdd(&cursor[d >> CSH], 1);
            grouped[g] = make_uint2((unsigned)d, rec);
        }
    }
    for (int i = lim4 + tid; i < lim; i += 256) {
        int e = base + i;
        int d = dst[e];
        unsigned rec = ((unsigned)f2bf(w[e]) << 16) | (unsigned)src[e];
        int g = atomicAdd(&cursor[d >> CSH], 1);
        grouped[g] = make_uint2((unsigned)d, rec);
    }
    __syncthreads();
    // flush: contiguous per-bin runs to global (avg run = lim/98 ~ 16 edges = 128B)
    for (int i = tid; i < lim; i += 256) {
        uint2 v = grouped[i];
        int b = (int)(v.x >> CSH);
        int off = gbase[b] + (i - startb[b]);
        if (off < CBCAP)
            binned[(size_t)b * CBCAP + (size_t)off] = v;
    }
}

// ---------------- fused: csr-build (391 blocks) || gemm tf (768 blocks) ----------------
// csr depends on partition; gemm is independent -> fusing them lets csr's latency-bound
// binned reads hide under gemm's MFMA waves on the same CUs instead of serializing as
// separate launches. csr blocks take blockIdx < nfb (dispatched first). 52 KB LDS union.
__global__ __launch_bounds__(256) void csr_gemm(
    const uint2* __restrict__ binned, const int* __restrict__ gcnt,
    unsigned* __restrict__ ep, int* __restrict__ cnt,
    const float* __restrict__ feat, const float* __restrict__ Wm,
    unsigned short* __restrict__ tf, int N)
{
    __shared__ char smem[52224] __attribute__((aligned(16)));
    const int tid = threadIdx.x;
    const int nfb = (N + 127) >> 7;

    if ((int)blockIdx.x < nfb) {
        // ---- csr role: build plane-major padded CSR for a 128-node fine bin ----
        unsigned* rowsT = reinterpret_cast<unsigned*>(smem);          // 32768 B
        int* lcnt       = reinterpret_cast<int*>(smem + 32768);       // 512 B
        int* maxcp      = reinterpret_cast<int*>(smem + 32768 + 512);
        const int fb = blockIdx.x;
        const int d0 = fb << 7;
        const int cb = fb >> 2;

        if (tid < 128) lcnt[tid] = 0;
        __syncthreads();
        int len = gcnt[cb];
        len = len < CBCAP ? len : CBCAP;
        const uint2* bp = binned + (size_t)cb * CBCAP;
        const int len2 = len & ~1;
        for (int i = tid * 2; i < len2; i += 512) {     // uint4 = 2 records
            const uint4 v2 = *reinterpret_cast<const uint4*>(bp + i);
            int da = (int)v2.x;
            if ((da >> 7) == fb) {
                int pos = atomicAdd(&lcnt[da & 127], 1);
                if (pos < CAP) rowsT[pos * 128 + (da & 127)] = v2.y;
            }
            int db = (int)v2.z;
            if ((db >> 7) == fb) {
                int pos = atomicAdd(&lcnt[db & 127], 1);
                if (pos < CAP) rowsT[pos * 128 + (db & 127)] = v2.w;
            }
        }
        for (int i = len2 + tid; i < len; i += 256) {   // <=1 leftover record
            uint2 v = bp[i];
            int d = (int)v.x;
            if ((d >> 7) == fb) {
                int pos = atomicAdd(&lcnt[d & 127], 1);
                if (pos < CAP) rowsT[pos * 128 + (d & 127)] = v.y;
            }
        }
        __syncthreads();
        if (tid == 0) {
            int m = 0;
            for (int j = 0; j < 128; ++j) m = m > lcnt[j] ? m : lcnt[j];
            *maxcp = m < CAP ? m : CAP;
        }
        __syncthreads();
        const int pu = *maxcp;
        for (int idx = tid; idx < (pu << 7); idx += 256) {
            int p = idx >> 7, j = idx & 127;
            int d = d0 + j;
            if (d < N) ep[(size_t)p * N + d] = rowsT[idx];   // 512B runs, coalesced
        }
        if (tid < 128) {
            int d = d0 + tid;
            if (d < N) cnt[d] = lcnt[tid];
        }
        return;
    }

    // ---- gemm role: tf = bf16(feat @ W^T), MFMA (proven code) ----
    unsigned short* Ws = reinterpret_cast<unsigned short*>(smem);          // 34816 B
    unsigned short* Ds = reinterpret_cast<unsigned short*>(smem + 34816);  // 17408 B

    for (int idx = tid; idx < 128 * 128 / 4; idx += 256) {
        int r = idx >> 5;
        int c = (idx & 31) * 4;
        const float4 v = reinterpret_cast<const float4*>(Wm)[idx];
        ushortx4 s;
        s[0] = f2bf(v.x); s[1] = f2bf(v.y); s[2] = f2bf(v.z); s[3] = f2bf(v.w);
        *reinterpret_cast<ushortx4*>(&Ws[r * WS_STRIDE + c]) = s;
    }
    __syncthreads();

    const int lane = tid & 63;
    const int wave = tid >> 6;
    const int kq = (lane >> 4) * 8;
    const int ntiles = (N + 63) >> 6;

    for (int t = blockIdx.x - nfb; t < ntiles; t += GEMM_BLOCKS) {
        const int node0 = t * 64;
        const int mr = node0 + wave * 16 + (lane & 15);
        const float* arow = feat + (size_t)(mr < N ? mr : (N - 1)) * D + kq;

        short8 a[4];
#pragma unroll
        for (int kt = 0; kt < 4; ++kt) {
            const float* p = arow + kt * 32;
            const float4 lo = *reinterpret_cast<const float4*>(p);
            const float4 hi = *reinterpret_cast<const float4*>(p + 4);
            short8 v;
            v[0] = (short)f2bf(lo.x); v[1] = (short)f2bf(lo.y);
            v[2] = (short)f2bf(lo.z); v[3] = (short)f2bf(lo.w);
            v[4] = (short)f2bf(hi.x); v[5] = (short)f2bf(hi.y);
            v[6] = (short)f2bf(hi.z); v[7] = (short)f2bf(hi.w);
            a[kt] = v;
        }

        floatx4 acc[8];
#pragma unroll
        for (int nt = 0; nt < 8; ++nt) {
            acc[nt][0] = 0.f; acc[nt][1] = 0.f; acc[nt][2] = 0.f; acc[nt][3] = 0.f;
        }
#pragma unroll
        for (int nt = 0; nt < 8; ++nt) {
            const unsigned short* brow = &Ws[(nt * 16 + (lane & 15)) * WS_STRIDE + kq];
#pragma unroll
            for (int kt = 0; kt < 4; ++kt) {
                short8 b = *reinterpret_cast<const short8*>(brow + kt * 32);
                acc[nt] = __builtin_amdgcn_mfma_f32_16x16x32_bf16(a[kt], b, acc[nt], 0, 0, 0);
            }
        }

        __syncthreads();   // prev tile's Ds readers done
        const int mlocal = wave * 16 + (lane >> 4) * 4;
        const int col = lane & 15;
#pragma unroll
        for (int r = 0; r < 4; ++r) {
            unsigned short* drow = &Ds[(mlocal + r) * DS_STRIDE + col];
#pragma unroll
            for (int nt = 0; nt < 8; ++nt)
                drow[nt * 16] = f2bf(acc[nt][r]);
        }
        __syncthreads();

        // 64 rows x 16 chunks of 16B; coalesced, row-major tf
        for (int idx = tid; idx < 64 * 16; idx += 256) {
            int row = idx >> 4;
            int chunk = idx & 15;
            int m = node0 + row;
            if (m < N) {
                uint4 v = *reinterpret_cast<const uint4*>(&Ds[row * DS_STRIDE + chunk * 8]);
                *reinterpret_cast<uint4*>(tf + (size_t)m * D + chunk * 8) = v;
            }
        }
    }
}

// ---------------- gather-reduce (unchanged, proven): out = relu(sum w*tf[src] + b) ----------------
__global__ __launch_bounds__(256) void csr_gather_bf16(
    const unsigned short* __restrict__ tf, const unsigned* __restrict__ ep,
    const int* __restrict__ cnt, const float* __restrict__ bias,
    float* __restrict__ out, int N)
{
    int node = blockIdx.x * 16 + (threadIdx.x >> 4);
    if (node >= N) return;
    const int lane = threadIdx.x & 15;
    const int c = lane << 3;               // 8 bf16 per lane
    const unsigned* col = ep + node;       // stride N per plane
    int end = cnt[node];
    end = end < CAP ? end : CAP;
    int p = 0;
    float a0 = 0.f, a1 = 0.f, a2 = 0.f, a3 = 0.f;
    float a4 = 0.f, a5 = 0.f, a6 = 0.f, a7 = 0.f;

#define ACC8(Q, W)                                       \
    a0 += __uint_as_float((Q).x << 16) * (W);            \
    a1 += __uint_as_float((Q).x & 0xffff0000u) * (W);    \
    a2 += __uint_as_float((Q).y << 16) * (W);            \
    a3 += __uint_as_float((Q).y & 0xffff0000u) * (W);    \
    a4 += __uint_as_float((Q).z << 16) * (W);            \
    a5 += __uint_as_float((Q).z & 0xffff0000u) * (W);    \
    a6 += __uint_as_float((Q).w << 16) * (W);            \
    a7 += __uint_as_float((Q).w & 0xffff0000u) * (W);

    for (; p + 7 < end; p += 8) {
        unsigned r[8];
#pragma unroll
        for (int j = 0; j < 8; ++j) r[j] = col[(size_t)(p + j) * N];
        uint4 q[8];
        float wv[8];
#pragma unroll
        for (int j = 0; j < 8; ++j) {
            q[j] = *reinterpret_cast<const uint4*>(tf + (size_t)(r[j] & 0xffffu) * D + c);
            wv[j] = __uint_as_float(r[j] & 0xffff0000u);
        }
#pragma unroll
        for (int j = 0; j < 8; ++j) { ACC8(q[j], wv[j]) }
    }
    for (; p + 3 < end; p += 4) {
        unsigned r[4];
#pragma unroll
        for (int j = 0; j < 4; ++j) r[j] = col[(size_t)(p + j) * N];
        uint4 q[4];
        float wv[4];
#pragma unroll
        for (int j = 0; j < 4; ++j) {
            q[j] = *reinterpret_cast<const uint4*>(tf + (size_t)(r[j] & 0xffffu) * D + c);
            wv[j] = __uint_as_float(r[j] & 0xffff0000u);
        }
#pragma unroll
        for (int j = 0; j < 4; ++j) { ACC8(q[j], wv[j]) }
    }
    for (; p < end; ++p) {
        unsigned r = col[(size_t)p * N];
        float wv = __uint_as_float(r & 0xffff0000u);
        uint4 q = *reinterpret_cast<const uint4*>(tf + (size_t)(r & 0xffffu) * D + c);
        ACC8(q, wv)
    }
#undef ACC8

    const float4 bv0 = *reinterpret_cast<const float4*>(bias + c);
    const float4 bv1 = *reinterpret_cast<const float4*>(bias + c + 4);
    float4 r0, r1;
    r0.x = fmaxf(a0 + bv0.x, 0.f);
    r0.y = fmaxf(a1 + bv0.y, 0.f);
    r0.z = fmaxf(a2 + bv0.z, 0.f);
    r0.w = fmaxf(a3 + bv0.w, 0.f);
    r1.x = fmaxf(a4 + bv1.x, 0.f);
    r1.y = fmaxf(a5 + bv1.y, 0.f);
    r1.z = fmaxf(a6 + bv1.z, 0.f);
    r1.w = fmaxf(a7 + bv1.w, 0.f);
    float* o = out + (size_t)node * D + c;
    *reinterpret_cast<float4*>(o) = r0;
    *reinterpret_cast<float4*>(o + 4) = r1;
}

// ---------------- tier-1 fallback: atomic scatter + fp32 GEMM ----------------
__global__ __launch_bounds__(256) void edge_scatter(
    const float* __restrict__ feat, const int* __restrict__ src,
    const int* __restrict__ dst, const float* __restrict__ w,
    float* __restrict__ agg, int E)
{
    long long idx = (long long)blockIdx.x * 256 + threadIdx.x;
    int e = (int)(idx >> 5);
    if (e >= E) return;
    int c = ((int)idx & 31) << 2;
    int s = src[e];
    int d = dst[e];
    float wv = w[e];
    const float4 f = *reinterpret_cast<const float4*>(feat + (size_t)s * D + c);
    float* a = agg + (size_t)d * D + c;
    atomicAdd(a + 0, f.x * wv);
    atomicAdd(a + 1, f.y * wv);
    atomicAdd(a + 2, f.z * wv);
    atomicAdd(a + 3, f.w * wv);
}

__global__ __launch_bounds__(256) void node_linear(
    const float* __restrict__ in, const float* __restrict__ Wm,
    const float* __restrict__ bias, float* __restrict__ out, int N)
{
    __shared__ float Bs[64 * BS_STRIDE];
    __shared__ float As[TILE_M * AS_STRIDE];
    const int tid = threadIdx.x;
    const int tx = tid & 15;
    const int ty = tid >> 4;
    const int node0 = blockIdx.x * TILE_M;
    float acc[4][8];
#pragma unroll
    for (int i = 0; i < 4; ++i)
#pragma unroll
        for (int jj = 0; jj < 8; ++jj) acc[i][jj] = 0.0f;
    for (int kh = 0; kh < 2; ++kh) {
        const int kbase = kh * 64;
        for (int i = tid; i < 128 * 64; i += 256) {
            int j = i >> 6, k = i & 63;
            Bs[k * BS_STRIDE + j] = Wm[j * 128 + kbase + k];
        }
        for (int i = tid; i < TILE_M * 64; i += 256) {
            int m = i >> 6, k = i & 63;
            int n = node0 + m;
            As[m * AS_STRIDE + k] = (n < N) ? in[(size_t)n * D + kbase + k] : 0.0f;
        }
        __syncthreads();
        for (int k0 = 0; k0 < 64; k0 += 4) {
            float a[4][4];
#pragma unroll
            for (int i = 0; i < 4; ++i) {
                const float4 v = *reinterpret_cast<const float4*>(&As[(ty * 4 + i) * AS_STRIDE + k0]);
                a[i][0] = v.x; a[i][1] = v.y; a[i][2] = v.z; a[i][3] = v.w;
            }
#pragma unroll
            for (int kk = 0; kk < 4; ++kk) {
                float bv[8];
#pragma unroll
                for (int jj = 0; jj < 8; ++jj) bv[jj] = Bs[(k0 + kk) * BS_STRIDE + tx + 16 * jj];
#pragma unroll
                for (int i = 0; i < 4; ++i)
#pragma unroll
                    for (int jj = 0; jj < 8; ++jj) acc[i][jj] += a[i][kk] * bv[jj];
            }
        }
        __syncthreads();
    }
    float bv[8];
#pragma unroll
    for (int jj = 0; jj < 8; ++jj) bv[jj] = bias[tx + 16 * jj];
#pragma unroll
    for (int i = 0; i < 4; ++i) {
        int n = node0 + ty * 4 + i;
        if (n < N) {
            float* o = out + (size_t)n * D;
#pragma unroll
            for (int jj = 0; jj < 8; ++jj) {
                float v = acc[i][jj] + bv[jj];
                o[tx + 16 * jj] = v > 0.0f ? v : 0.0f;
            }
        }
    }
}

extern "C" void kernel_launch(void* const* d_in, const int* in_sizes, int n_in,
                              void* d_out, int out_size, void* d_ws, size_t ws_size,
                              hipStream_t stream) {
    const float* feat = (const float*)d_in[0];
    const int*   src  = (const int*)d_in[1];
    const int*   dst  = (const int*)d_in[2];
    const float* w    = (const float*)d_in[3];
    const float* Wm   = (const float*)d_in[4];
    const float* bias = (const float*)d_in[5];
    float* out = (float*)d_out;

    const int N = in_sizes[0] / D;   // 50000
    const int E = in_sizes[1];       // 800000

    const int ncb = (N + 511) >> CSH;      // coarse bins (98)
    const int nfb = (N + 127) >> 7;        // fine bins   (391)

    const size_t ep_b     = (size_t)N * CAP * 4;              // plane-major CSR, 12.8 MB
    const size_t cnt_b    = (size_t)N * sizeof(int);
    const size_t tf_b     = (size_t)N * D * 2;
    const size_t binned_b = (size_t)ncb * CBCAP * sizeof(uint2);  // 12.8 MB
    const size_t gcnt_b   = 128 * sizeof(int);
    auto align_up = [](size_t x) { return (x + 255) & ~(size_t)255; };

    const size_t need_full = align_up(ep_b) + align_up(cnt_b) + align_up(tf_b) +
                             align_up(binned_b) + align_up(gcnt_b);

    // fast path: src ids fit 16 bits, pass-1 LDS chunk fits, padded-CSR sane, ws fits
    if (ws_size >= need_full && N <= 65536 &&
        E <= P1_BLOCKS * P1_CHUNK &&
        (long long)E <= (long long)N * (CAP / 4)) {
        char* p = (char*)d_ws;
        unsigned* ep     = (unsigned*)p;       p += align_up(ep_b);
        int*      cnt    = (int*)p;            p += align_up(cnt_b);
        unsigned short* tf = (unsigned short*)p; p += align_up(tf_b);
        uint2*    binned = (uint2*)p;          p += align_up(binned_b);
        int*      gcnt   = (int*)p;

        (void)hipMemsetAsync(gcnt, 0, gcnt_b, stream);   // 512 B
        edge_partition<<<P1_BLOCKS, 256, 0, stream>>>(src, dst, w, gcnt, binned, N, E);
        csr_gemm<<<nfb + GEMM_BLOCKS, 256, 0, stream>>>(binned, gcnt, ep, cnt,
                                                        feat, Wm, tf, N);
        csr_gather_bf16<<<(N + 15) / 16, 256, 0, stream>>>(tf, ep, cnt, bias, out, N);
    } else {
        // fallback: atomic scatter into out, then in-place fp32 linear
        (void)hipMemsetAsync(out, 0, (size_t)N * D * sizeof(float), stream);
        long long st = (long long)E * 32;
        edge_scatter<<<(int)((st + 255) / 256), 256, 0, stream>>>(feat, src, dst, w, out, E);
        node_linear<<<(N + TILE_M - 1) / TILE_M, 256, 0, stream>>>(out, Wm, bias, out, N);
    }
}